// Round 13
// baseline (563.043 us; speedup 1.0000x reference)
//
#include <hip/hip_runtime.h>
#include <cstddef>

#define B_SZ 8
#define N_PTS 1024
#define KNN_K 20
#define CAT_C 512
#define BN_EPS 1e-5f

typedef unsigned short u16;
typedef unsigned int u32;
typedef __bf16 bf16x8 __attribute__((ext_vector_type(8)));
typedef float f32x4 __attribute__((ext_vector_type(4)));

// ---------------- transpose x (B,3,N) -> feat0 (B,N,4) (col 3 pre-zeroed) ----------------
__global__ __launch_bounds__(256) void transpose_x(const float* __restrict__ x,
                                                   float* __restrict__ feat0) {
  int t = blockIdx.x * 256 + threadIdx.x;
  if (t >= B_SZ * 3 * N_PTS) return;
  int b = t / (3 * N_PTS);
  int r = t - b * 3 * N_PTS;
  int c = r / N_PTS;
  int n = r - c * N_PTS;
  feat0[((size_t)(b * N_PTS + n)) * 4 + c] = x[t];
}

// ---------------- squared norms per point ----------------
__global__ __launch_bounds__(256) void xnorm_kernel(const float* __restrict__ feat, int lda,
                                                    int C, float* __restrict__ x2) {
  int p = blockIdx.x * 256 + threadIdx.x;
  if (p >= 8192) return;
  const float* r = feat + (size_t)p * lda;
  float s = 0.f;
  for (int c = 0; c < C; c += 4) {
    float4 v = *(const float4*)(r + c);
    s = fmaf(v.x, v.x, s); s = fmaf(v.y, v.y, s);
    s = fmaf(v.z, v.z, s); s = fmaf(v.w, v.w, s);
  }
  x2[p] = s;
}

// ---------------- pack candidates: feat (b,p,4k4..) -> pack[(b*C4+k4)*1024+p] (float4) ----
__global__ __launch_bounds__(256) void pack_kernel(const float* __restrict__ feat, int lda,
                                                   int C4, float4* __restrict__ packb) {
  int t = blockIdx.x * 256 + threadIdx.x;
  if (t >= 8192 * C4) return;
  int p = t & 1023;
  int bk = t >> 10;
  int k4 = bk % C4, b = bk / C4;
  packb[t] = *(const float4*)(feat + (size_t)(b * 1024 + p) * lda + (k4 << 2));
}

// ---- DPP u32-min reduce stage (identity 0x7fffffff), tree verified in R11 ----
#define DPP_MIN_STAGE(CTRL)                                                          \
  {                                                                                  \
    int nb = __builtin_amdgcn_update_dpp((int)0x7fffffff, mc,                        \
                                         (CTRL), 0xF, 0xF, false);                   \
    mc = (nb < mc) ? nb : mc;                                                        \
  }

// ---------------- fused KNN: distances in-register + radix-select top-20 --------------
// 512 threads = 8 waves; one row per wave; lane holds cols j*64+lane.
// Selection: 4-pass 8-bit radix on monotone u32 value-key finds exact 20th-largest T;
// emit all >T (order-free: downstream max/sum over k are commutative and BN sums are
// already atomic-binned), then r smallest cols among ==T (exact top_k tie semantics).
// Hist lives in the dead xms buffer (per-wave 256-bin slice, wave-synchronous LDS).
__global__ __launch_bounds__(512) void knn_fused(const float* __restrict__ feat, int lda,
                                                 int C4, const float4* __restrict__ pack,
                                                 const float* __restrict__ x2,
                                                 int* __restrict__ idxout) {
  __shared__ float4 xms[1024];        // 16 KB: candidates' k-slice; later: radix hist
  __shared__ float4 xn_sh[8 * 32];    // 4 KB: query rows; later: aux broadcast slots
  int tid = threadIdx.x;
  int w = tid >> 6, lane = tid & 63;
  int row0 = blockIdx.x * 8;
  int b = row0 >> 10;
  int row = row0 + w;
  const float4* packB = pack + (size_t)b * C4 * 1024;

  if (tid < 8 * C4) {
    int r = tid / C4, q = tid - r * C4;
    xn_sh[r * 32 + q] = *(const float4*)(feat + (size_t)(row0 + r) * lda + (q << 2));
  }

  float acc[16];
  #pragma unroll
  for (int j = 0; j < 16; ++j) acc[j] = 0.f;

  for (int k4 = 0; k4 < C4; ++k4) {
    xms[tid] = packB[k4 * 1024 + tid];
    xms[tid + 512] = packB[k4 * 1024 + tid + 512];
    __syncthreads();
    float4 xn = xn_sh[w * 32 + k4];
    #pragma unroll
    for (int j = 0; j < 16; ++j) {
      float4 xm = xms[j * 64 + lane];
      acc[j] = fmaf(xn.x, xm.x, acc[j]);
      acc[j] = fmaf(xn.y, xm.y, acc[j]);
      acc[j] = fmaf(xn.z, xm.z, acc[j]);
      acc[j] = fmaf(xn.w, xm.w, acc[j]);
    }
    __syncthreads();   // last iteration: all waves done with xms/xn_sh -> reusable
  }

  // distances -> monotone u32 keys (same fp expression as proven kernels; +0.0f
  // canonicalizes -0 so equal floats give equal keys)
  const float* x2b = x2 + b * N_PTS;
  float x2n = x2[row];
  u32 uv[16];
  #pragma unroll
  for (int j = 0; j < 16; ++j) {
    float v = ((2.f * acc[j] - x2n) - x2b[j * 64 + lane]) + 0.0f;
    u32 u = __float_as_uint(v);
    uv[j] = u ^ ((u32)(-(int)(u >> 31)) | 0x80000000u);
  }

  // per-wave LDS slices (disjoint; wave-synchronous, no barriers needed)
  u32* hist = (u32*)xms + w * 256;           // 256 bins; slot g counts digit 255-g
  volatile u32* aux = (u32*)xn_sh + w * 8;   // [0]=emit cnt, [1]=digit, [2]=above

  u32 maskj = 0xFFFFu;   // j's whose key matches the prefix chosen so far
  int need = KNN_K;
  u32 T = 0;
  #pragma unroll
  for (int pass = 0; pass < 4; ++pass) {
    int shift = 24 - 8 * pass;
    hist[lane * 4 + 0] = 0; hist[lane * 4 + 1] = 0;
    hist[lane * 4 + 2] = 0; hist[lane * 4 + 3] = 0;
    #pragma unroll
    for (int j = 0; j < 16; ++j) {
      if (maskj & (1u << j)) {
        u32 d = (uv[j] >> shift) & 255u;
        atomicAdd(&hist[255u - d], 1u);
      }
    }
    u32 c0 = hist[lane * 4 + 0], c1 = hist[lane * 4 + 1];
    u32 c2 = hist[lane * 4 + 2], c3 = hist[lane * 4 + 3];
    u32 s = c0 + c1 + c2 + c3;
    // inclusive prefix scan over lanes (slot order = digit descending)
    u32 P = s;
    #pragma unroll
    for (int off = 1; off < 64; off <<= 1) {
      u32 t = (u32)__shfl_up((int)P, off, 64);
      if (lane >= off) P += t;
    }
    u32 E = P - s;   // exclusive: count of digits strictly greater than my slots
    if ((int)E < need && need <= (int)P) {   // exactly one lane crosses
      u32 cum = E, dsel, above;
      if ((int)(cum + c0) >= need)                { dsel = 255u - (u32)(lane * 4 + 0); above = cum; }
      else if ((int)(cum + c0 + c1) >= need)      { dsel = 255u - (u32)(lane * 4 + 1); above = cum + c0; }
      else if ((int)(cum + c0 + c1 + c2) >= need) { dsel = 255u - (u32)(lane * 4 + 2); above = cum + c0 + c1; }
      else                                        { dsel = 255u - (u32)(lane * 4 + 3); above = cum + c0 + c1 + c2; }
      aux[1] = dsel; aux[2] = above;
    }
    u32 dstar = aux[1];        // wave-synchronous broadcast (same wave, program order)
    u32 above = aux[2];
    need -= (int)above;
    T = (T << 8) | dstar;
    u32 nm = 0;
    #pragma unroll
    for (int j = 0; j < 16; ++j)
      if ((maskj & (1u << j)) && (((uv[j] >> shift) & 255u) == dstar)) nm |= (1u << j);
    maskj = nm;
  }

  // emit: all keys > T at atomic-assigned slots (order-free), then r smallest
  // cols among == T (exact top_k tie-break: smallest index first)
  if (lane == 0) aux[0] = 0;
  int base = row * KNN_K;
  #pragma unroll
  for (int j = 0; j < 16; ++j) {
    if (uv[j] > T) {
      u32 pos = atomicAdd((u32*)&aux[0], 1u);
      idxout[base + pos] = j * 64 + lane;
    }
  }
  int tieBase = KNN_K - need;   // == count(>T)
  int last = -1;
  for (int t = 0; t < need; ++t) {
    int mc = 0x7fffffff;
    #pragma unroll
    for (int j = 15; j >= 0; --j) {     // descending j ends at smallest valid col
      int col = j * 64 + lane;
      if (uv[j] == T && col > last) mc = col;
    }
    DPP_MIN_STAGE(0x111)   // row_shr:1   (tree verified in R11)
    DPP_MIN_STAGE(0x112)   // row_shr:2
    DPP_MIN_STAGE(0x114)   // row_shr:4
    DPP_MIN_STAGE(0x118)   // row_shr:8
    DPP_MIN_STAGE(0x142)   // row_bcast15
    DPP_MIN_STAGE(0x143)   // row_bcast31
    int wmin = __builtin_amdgcn_readlane(mc, 63);
    if (lane == 0) idxout[base + tieBase + t] = wmin;
    last = wmin;
  }
}

// ---------------- build combined weight Wc (fp32): [w1-w2 | w2], K=C rows x 2O cols ----------------
__global__ __launch_bounds__(256) void build_wc(const float* __restrict__ w, int C, int O,
                                                float* __restrict__ wc) {
  int t = blockIdx.x * 256 + threadIdx.x;
  int twoO = 2 * O;
  if (t >= C * twoO) return;
  int c = t / twoO, j = t - c * twoO;
  float v;
  if (j < O) v = w[j * (2 * C) + c] - w[j * (2 * C) + C + c];
  else       v = w[(j - O) * (2 * C) + C + c];
  wc[t] = v;
}

// ---------------- fp32 GEMM (edge layers): C[M,N] = A[M,K](lda) * B[K,N] ----------------
__global__ __launch_bounds__(256) void gemm_kernel(const float* __restrict__ A, int lda,
                                                   const float* __restrict__ Bm,
                                                   float* __restrict__ Cm,
                                                   int M, int N, int K) {
  __shared__ float As[16][64];
  __shared__ float Bs[16][68];
  int tx = threadIdx.x & 15, ty = threadIdx.x >> 4;
  int bn0 = blockIdx.x * 64, bm0 = blockIdx.y * 64;
  float acc[4][4];
  #pragma unroll
  for (int i = 0; i < 4; ++i)
    #pragma unroll
    for (int j = 0; j < 4; ++j) acc[i][j] = 0.f;

  for (int k0 = 0; k0 < K; k0 += 16) {
    {
      int t = threadIdx.x;
      int m = t >> 2, kb = (t & 3) * 4;
      const float* ap = A + (size_t)(bm0 + m) * lda + k0 + kb;
      #pragma unroll
      for (int i = 0; i < 4; ++i) As[kb + i][m] = (k0 + kb + i < K) ? ap[i] : 0.f;
      int r = t >> 4, c4 = (t & 15) * 4;
      float4 bv = make_float4(0.f, 0.f, 0.f, 0.f);
      if (k0 + r < K) bv = *(const float4*)(Bm + (size_t)(k0 + r) * N + bn0 + c4);
      *(float4*)&Bs[r][c4] = bv;
    }
    __syncthreads();
    #pragma unroll
    for (int k = 0; k < 16; ++k) {
      float a0[4];
      #pragma unroll
      for (int i = 0; i < 4; ++i) a0[i] = As[k][ty * 4 + i];
      float4 bv = *(const float4*)&Bs[k][tx * 4];
      float b0[4] = {bv.x, bv.y, bv.z, bv.w};
      #pragma unroll
      for (int i = 0; i < 4; ++i)
        #pragma unroll
        for (int j = 0; j < 4; ++j) acc[i][j] = fmaf(a0[i], b0[j], acc[i][j]);
    }
    __syncthreads();
  }
  #pragma unroll
  for (int i = 0; i < 4; ++i) {
    float4 v = make_float4(acc[i][0], acc[i][1], acc[i][2], acc[i][3]);
    *(float4*)(Cm + (size_t)(bm0 + ty * 4 + i) * N + bn0 + tx * 4) = v;
  }
}

// ---------------- split fp32 -> bf16 hi/lo MFMA GEMM for layer 5, fused reduction ----------------
__device__ inline void split8(const float* __restrict__ p, bf16x8* hv, bf16x8* lv) {
  float4 a0 = *(const float4*)p, a1 = *(const float4*)(p + 4);
  float v[8] = {a0.x, a0.y, a0.z, a0.w, a1.x, a1.y, a1.z, a1.w};
  bf16x8 h, l;
  #pragma unroll
  for (int j = 0; j < 8; ++j) {
    __bf16 hj = (__bf16)v[j];
    h[j] = hj;
    l[j] = (__bf16)(v[j] - (float)hj);
  }
  *hv = h; *lv = l;
}

__global__ __launch_bounds__(256) void gemm_split_red(const float* __restrict__ A, int lda,
                                                      const float* __restrict__ Bt, int ldb,
                                                      float* __restrict__ parts, int K) {
  __shared__ u16 Ah[128 * 64];
  __shared__ u16 Al[128 * 64];
  __shared__ u16 Bh[128 * 64];
  __shared__ u16 Bl[128 * 64];
  int tid = threadIdx.x;
  int wave = tid >> 6, lane = tid & 63;
  int wr = wave >> 1, wc = wave & 1;
  int bn0 = blockIdx.x * 128, bm0 = blockIdx.y * 128;
  int lrow = lane & 15;
  int kgrp = lane >> 4;

  f32x4 acc[4][4];
  #pragma unroll
  for (int i = 0; i < 4; ++i)
    #pragma unroll
    for (int j = 0; j < 4; ++j) acc[i][j] = (f32x4){0.f, 0.f, 0.f, 0.f};

  for (int k0 = 0; k0 < K; k0 += 64) {
    #pragma unroll
    for (int i = 0; i < 4; ++i) {
      int chunk = tid + i * 256;        // 0..1023
      int row = chunk >> 3;             // 0..127
      int cc = (chunk & 7) * 8;         // fp32 col 0,8,..,56
      int byte = row * 128 + ((cc * 2) ^ ((row & 7) << 4));
      bf16x8 h, l;
      split8(A + (size_t)(bm0 + row) * lda + k0 + cc, &h, &l);
      *(bf16x8*)((char*)Ah + byte) = h;
      *(bf16x8*)((char*)Al + byte) = l;
      split8(Bt + (size_t)(bn0 + row) * ldb + k0 + cc, &h, &l);
      *(bf16x8*)((char*)Bh + byte) = h;
      *(bf16x8*)((char*)Bl + byte) = l;
    }
    __syncthreads();
    #pragma unroll
    for (int kk = 0; kk < 64; kk += 32) {
      int kb = (kk + kgrp * 8) * 2;
      bf16x8 afh[4], afl[4], bfh[4], bfl[4];
      #pragma unroll
      for (int f = 0; f < 4; ++f) {
        int arow = wr * 64 + f * 16 + lrow;
        int abyte = arow * 128 + (kb ^ ((arow & 7) << 4));
        afh[f] = *(const bf16x8*)((const char*)Ah + abyte);
        afl[f] = *(const bf16x8*)((const char*)Al + abyte);
        int brow = wc * 64 + f * 16 + lrow;
        int bbyte = brow * 128 + (kb ^ ((brow & 7) << 4));
        bfh[f] = *(const bf16x8*)((const char*)Bh + bbyte);
        bfl[f] = *(const bf16x8*)((const char*)Bl + bbyte);
      }
      #pragma unroll
      for (int fm = 0; fm < 4; ++fm)
        #pragma unroll
        for (int fn = 0; fn < 4; ++fn) {
          acc[fm][fn] = __builtin_amdgcn_mfma_f32_16x16x32_bf16(afh[fm], bfh[fn], acc[fm][fn], 0, 0, 0);
          acc[fm][fn] = __builtin_amdgcn_mfma_f32_16x16x32_bf16(afl[fm], bfh[fn], acc[fm][fn], 0, 0, 0);
          acc[fm][fn] = __builtin_amdgcn_mfma_f32_16x16x32_bf16(afh[fm], bfl[fn], acc[fm][fn], 0, 0, 0);
        }
    }
    __syncthreads();
  }

  // fused per-tile reduction over the 128 rows
  float* scratch = (float*)Ah;
  int contrib = wr * 4 + kgrp;
  #pragma unroll
  for (int fn = 0; fn < 4; ++fn) {
    float mx = -3.4e38f, mn = 3.4e38f, s1 = 0.f, s2 = 0.f;
    #pragma unroll
    for (int fm = 0; fm < 4; ++fm)
      #pragma unroll
      for (int r = 0; r < 4; ++r) {
        float v = acc[fm][fn][r];
        mx = fmaxf(mx, v); mn = fminf(mn, v);
        s1 += v; s2 = fmaf(v, v, s2);
      }
    int col = wc * 64 + fn * 16 + lrow;
    float* sp = scratch + (contrib * 128 + col) * 4;
    sp[0] = mx; sp[1] = mn; sp[2] = s1; sp[3] = s2;
  }
  __syncthreads();
  if (tid < 128) {
    float mx = -3.4e38f, mn = 3.4e38f, s1 = 0.f, s2 = 0.f;
    #pragma unroll
    for (int c2 = 0; c2 < 8; ++c2) {
      const float* sp = scratch + (c2 * 128 + tid) * 4;
      mx = fmaxf(mx, sp[0]); mn = fminf(mn, sp[1]);
      s1 += sp[2]; s2 += sp[3];
    }
    size_t o = (size_t)blockIdx.y * 1024 + bn0 + tid;
    parts[o] = mx;
    parts[65536 + o] = mn;
    parts[131072 + o] = s1;
    parts[196608 + o] = s2;
  }
}

// ---------------- edge aggregation: h = a + y[idx]; max/min over k + channel sums ----------------
__global__ __launch_bounds__(256) void aggregate_kernel(const float* __restrict__ ay,
                                                        const int* __restrict__ idxb, int O,
                                                        float* __restrict__ mx,
                                                        float* __restrict__ mn,
                                                        float* __restrict__ sumsbin) {
  __shared__ float ls[2][256];
  for (int i = threadIdx.x; i < 512; i += 256) ((float*)ls)[i] = 0.f;
  __syncthreads();

  int warp = threadIdx.x >> 6, lane = threadIdx.x & 63;
  int pt = blockIdx.x * 4 + warp;   // 0..8191
  int b = pt >> 10;
  int twoO = 2 * O;
  int U = O >> 6;
  const float* ayrow = ay + (size_t)pt * twoO;

  float av[4], s1[4], s2[4], vmx[4], vmn[4];
  for (int u = 0; u < U; ++u) {
    av[u] = ayrow[u * 64 + lane];
    s1[u] = 0.f; s2[u] = 0.f; vmx[u] = -3.4e38f; vmn[u] = 3.4e38f;
  }
  const int* ip = idxb + pt * KNN_K;
  for (int k = 0; k < KNN_K; ++k) {
    int j = ip[k];
    const float* yrow = ay + (size_t)(b * N_PTS + j) * twoO + O;
    for (int u = 0; u < U; ++u) {
      float v = av[u] + yrow[u * 64 + lane];
      s1[u] += v; s2[u] = fmaf(v, v, s2[u]);
      vmx[u] = fmaxf(vmx[u], v); vmn[u] = fminf(vmn[u], v);
    }
  }
  for (int u = 0; u < U; ++u) {
    int o = u * 64 + lane;
    mx[(size_t)pt * O + o] = vmx[u];
    mn[(size_t)pt * O + o] = vmn[u];
    atomicAdd(&ls[0][o], s1[u]);
    atomicAdd(&ls[1][o], s2[u]);
  }
  __syncthreads();
  int bin = blockIdx.x & 63;
  float* gb = sumsbin + (size_t)bin * 512;
  for (int o = threadIdx.x; o < O; o += 256) {
    atomicAdd(&gb[o], ls[0][o]);
    atomicAdd(&gb[256 + o], ls[1][o]);
  }
}

__global__ __launch_bounds__(256) void reduce_bins(const float* __restrict__ sumsbin,
                                                   float* __restrict__ sums, int O) {
  int o = threadIdx.x;
  if (o >= O) return;
  float a = 0.f, c = 0.f;
  for (int bin = 0; bin < 64; ++bin) {
    a += sumsbin[bin * 512 + o];
    c += sumsbin[bin * 512 + 256 + o];
  }
  sums[o] = a;
  sums[256 + o] = c;
}

// ---------------- finalize edge layer: BN + relu on (max or min depending on sign) ----------------
__global__ __launch_bounds__(256) void finalize_edge(const float* __restrict__ mx,
                                                     const float* __restrict__ mn,
                                                     const float* __restrict__ sums,
                                                     const float* __restrict__ g,
                                                     const float* __restrict__ beta,
                                                     int oshift,
                                                     float* __restrict__ outseg,
                                                     float cnt_inv) {
  int tid = blockIdx.x * 256 + threadIdx.x;
  int pt = tid >> oshift;
  int o = tid & ((1 << oshift) - 1);
  float s1 = sums[o], s2 = sums[256 + o];
  float mean = s1 * cnt_inv;
  float var = s2 * cnt_inv - mean * mean;
  float rstd = rsqrtf(var + BN_EPS);
  float sc = g[o] * rstd;
  float sel = (sc >= 0.f) ? mx[tid] : mn[tid];
  float v = (sel - mean) * sc + beta[o];
  outseg[(size_t)pt * CAT_C + o] = fmaxf(v, 0.f);
}

// ---------------- layer 5 finalize from tile partials ----------------
__global__ __launch_bounds__(256) void finalize5_fused(const float* __restrict__ parts,
                                                       const float* __restrict__ g,
                                                       const float* __restrict__ beta,
                                                       float* __restrict__ out) {
  int tid = blockIdx.x * 256 + threadIdx.x;   // 0..8191
  int b = tid >> 10, o = tid & 1023;
  const float* pmx = parts;
  const float* pmn = parts + 65536;
  const float* ps1 = parts + 131072;
  const float* ps2 = parts + 196608;
  float s1 = 0.f, s2 = 0.f;
  for (int t = 0; t < 64; ++t) { s1 += ps1[t * 1024 + o]; s2 += ps2[t * 1024 + o]; }
  float mx = -3.4e38f, mn = 3.4e38f;
  #pragma unroll
  for (int t = 0; t < 8; ++t) {
    mx = fmaxf(mx, pmx[(b * 8 + t) * 1024 + o]);
    mn = fminf(mn, pmn[(b * 8 + t) * 1024 + o]);
  }
  float mean = s1 * (1.0f / 8192.0f);
  float var = s2 * (1.0f / 8192.0f) - mean * mean;
  float rstd = rsqrtf(var + BN_EPS);
  float sc = g[o] * rstd;
  float sel = (sc >= 0.f) ? mx : mn;
  float v = (sel - mean) * sc + beta[o];
  out[tid] = fmaxf(v, 0.f);
}

extern "C" void kernel_launch(void* const* d_in, const int* in_sizes, int n_in,
                              void* d_out, int out_size, void* d_ws, size_t ws_size,
                              hipStream_t stream) {
  const float* x = (const float*)d_in[0];
  const float* w[5]  = {(const float*)d_in[1], (const float*)d_in[4], (const float*)d_in[7],
                        (const float*)d_in[10], (const float*)d_in[13]};
  const float* gg[5] = {(const float*)d_in[2], (const float*)d_in[5], (const float*)d_in[8],
                        (const float*)d_in[11], (const float*)d_in[14]};
  const float* bb[5] = {(const float*)d_in[3], (const float*)d_in[6], (const float*)d_in[9],
                        (const float*)d_in[12], (const float*)d_in[15]};
  float* out = (float*)d_out;

  float* W = (float*)d_ws;
  size_t off = 0;
  float* feat0   = W + off; off += (size_t)B_SZ * N_PTS * 4;   // stride-4 padded
  float* catbuf  = W + off; off += (size_t)8192 * CAT_C;
  int*   idxbuf  = (int*)(W + off); off += (size_t)8192 * KNN_K;
  float* aybuf   = W + off; off += (size_t)8192 * 1024;
  float* mxbuf   = W + off; off += (size_t)8192 * 256;
  float* mnbuf   = W + off; off += (size_t)8192 * 256;
  float* wcbuf   = W + off; off += (size_t)512 * 1024;
  float* sumsbin = W + off; off += (size_t)64 * 512;
  float* sums    = W + off; off += 512;
  float* parts   = W + off; off += (size_t)4 * 64 * 1024;  // L5 tile partials (mx,mn,s1,s2)
  float* x2buf   = W + off; off += 8192;
  float4* packbuf = (float4*)(W + off); off += (size_t)8192 * 32 * 4;  // [b][k4][1024] f4, 4MB

  hipMemsetAsync(feat0, 0, (size_t)B_SZ * N_PTS * 4 * sizeof(float), stream);
  transpose_x<<<(B_SZ * 3 * N_PTS + 255) / 256, 256, 0, stream>>>(x, feat0);

  const int Cs[4] = {4, 64, 64, 128};   // layer-0 padded to 4 (pad=0, values unchanged)
  const int Ks[4] = {3, 64, 64, 128};   // true K for the edge GEMM
  const int Os[4] = {64, 64, 128, 256};
  const int osh[4] = {6, 6, 7, 8};
  const int segin[4] = {0, 0, 64, 128};
  const int segout[4] = {0, 64, 128, 256};

  for (int l = 0; l < 4; ++l) {
    int C = Cs[l], O = Os[l], twoO = 2 * O;
    const float* featin = (l == 0) ? feat0 : (catbuf + segin[l]);
    int lda = (l == 0) ? 4 : CAT_C;
    int C4 = C / 4;

    xnorm_kernel<<<32, 256, 0, stream>>>(featin, lda, C, x2buf);
    pack_kernel<<<(8192 * C4 + 255) / 256, 256, 0, stream>>>(featin, lda, C4, packbuf);
    knn_fused<<<1024, 512, 0, stream>>>(featin, lda, C4, packbuf, x2buf, idxbuf);

    build_wc<<<(Ks[l] * twoO + 255) / 256, 256, 0, stream>>>(w[l], Ks[l], O, wcbuf);
    gemm_kernel<<<dim3(twoO / 64, 8192 / 64), 256, 0, stream>>>(featin, lda, wcbuf, aybuf,
                                                                8192, twoO, Ks[l]);
    hipMemsetAsync(sumsbin, 0, (size_t)64 * 512 * sizeof(float), stream);
    aggregate_kernel<<<2048, 256, 0, stream>>>(aybuf, idxbuf, O, mxbuf, mnbuf, sumsbin);
    reduce_bins<<<1, 256, 0, stream>>>(sumsbin, sums, O);
    finalize_edge<<<(8192 * O) / 256, 256, 0, stream>>>(mxbuf, mnbuf, sums, gg[l], bb[l],
                                                        osh[l], catbuf + segout[l],
                                                        1.0f / (8192.0f * KNN_K));
  }

  // layer 5: h5 = cat * w5^T via split-bf16 MFMA with fused per-tile reduction
  gemm_split_red<<<dim3(1024 / 128, 8192 / 128), 256, 0, stream>>>(catbuf, CAT_C, w[4], 512,
                                                                   parts, 512);
  finalize5_fused<<<8192 / 256, 256, 0, stream>>>(parts, gg[4], bb[4], out);
}

// Round 15
// 536.045 us; speedup vs baseline: 1.0504x; 1.0504x over previous
//
#include <hip/hip_runtime.h>
#include <cstddef>

#define B_SZ 8
#define N_PTS 1024
#define KNN_K 20
#define CAT_C 512
#define BN_EPS 1e-5f

typedef unsigned short u16;
typedef unsigned int u32;
typedef __bf16 bf16;
typedef __bf16 bf16x8 __attribute__((ext_vector_type(8)));
typedef float f32x4 __attribute__((ext_vector_type(4)));

// ---------------- transpose x (B,3,N) -> feat0 (B,N,4) (col 3 pre-zeroed) ----------------
__global__ __launch_bounds__(256) void transpose_x(const float* __restrict__ x,
                                                   float* __restrict__ feat0) {
  int t = blockIdx.x * 256 + threadIdx.x;
  if (t >= B_SZ * 3 * N_PTS) return;
  int b = t / (3 * N_PTS);
  int r = t - b * 3 * N_PTS;
  int c = r / N_PTS;
  int n = r - c * N_PTS;
  feat0[((size_t)(b * N_PTS + n)) * 4 + c] = x[t];
}

// ---------------- squared norms per point (exact fp32) ----------------
__global__ __launch_bounds__(256) void xnorm_kernel(const float* __restrict__ feat, int lda,
                                                    int C, float* __restrict__ x2) {
  int p = blockIdx.x * 256 + threadIdx.x;
  if (p >= 8192) return;
  const float* r = feat + (size_t)p * lda;
  float s = 0.f;
  for (int c = 0; c < C; c += 4) {
    float4 v = *(const float4*)(r + c);
    s = fmaf(v.x, v.x, s); s = fmaf(v.y, v.y, s);
    s = fmaf(v.z, v.z, s); s = fmaf(v.w, v.w, s);
  }
  x2[p] = s;
}

// ---------------- triple-split features into bf16 h/m/l, [8192][128] zero-padded --------
__global__ __launch_bounds__(256) void split_pack(const float* __restrict__ feat, int lda,
                                                  int C, bf16* __restrict__ packH,
                                                  bf16* __restrict__ packM,
                                                  bf16* __restrict__ packL) {
  int t = blockIdx.x * 256 + threadIdx.x;     // 8192*16 threads, 8 k's each
  if (t >= 8192 * 16) return;
  int p = t >> 4, k0 = (t & 15) * 8;
  bf16x8 h, m, l;
  #pragma unroll
  for (int e = 0; e < 8; ++e) {
    int k = k0 + e;
    float v = (k < C) ? feat[(size_t)p * lda + k] : 0.f;
    bf16 hb = (bf16)v;       float r1 = v - (float)hb;
    bf16 mb = (bf16)r1;      float r2 = r1 - (float)mb;
    bf16 lb = (bf16)r2;
    h[e] = hb; m[e] = mb; l[e] = lb;
  }
  *(bf16x8*)(packH + (size_t)p * 128 + k0) = h;
  *(bf16x8*)(packM + (size_t)p * 128 + k0) = m;
  *(bf16x8*)(packL + (size_t)p * 128 + k0) = l;
}

// ---- DPP value-reduce stages (tree verified bit-exact in R10/R11) ----
#define DPP_MAX_STAGE(CTRL)                                                          \
  {                                                                                  \
    int nb = __builtin_amdgcn_update_dpp((int)0xFF800000, __float_as_int(mx),        \
                                         (CTRL), 0xF, 0xF, false);                   \
    mx = fmaxf(mx, __int_as_float(nb));                                              \
  }
#define DPP_MIN_STAGE(CTRL)                                                          \
  {                                                                                  \
    int nb = __builtin_amdgcn_update_dpp((int)0x7fffffff, mc,                        \
                                         (CTRL), 0xF, 0xF, false);                   \
    mc = (nb < mc) ? nb : mc;                                                        \
  }

// ---------------- KNN via triple-split bf16 MFMA distances + R11 selection --------------
// Block = 512 thr / 8 waves = 16 query rows x 1024 cols. A (16x128, 3 halves) in LDS
// (gemm_split_red swizzle, R14-functionally-verified); B fragments from packs (L2).
// 8 product terms (hh',hm',mh',mm',hl',lh',ml',lm') -> ~2^-24 rel distance error
// (fp32-chain level; R14's 3-term 2^-16 flipped KNN boundaries). Fragments processed
// in two halves of 4 so acc stays 16 VGPRs (R6-R8 spill trap avoided).
__global__ __launch_bounds__(512) void knn_mfma(const bf16* __restrict__ packH,
                                                const bf16* __restrict__ packM,
                                                const bf16* __restrict__ packL,
                                                const float* __restrict__ x2,
                                                int nks,
                                                int* __restrict__ idxout) {
  __shared__ u16 Ah[16 * 128];        // 4KB each, row stride 256B, XOR-swizzled
  __shared__ u16 Am[16 * 128];
  __shared__ u16 Al[16 * 128];
  __shared__ float Ds[16 * 1028];     // 65.8KB, padded stride (2-way aliasing = free)
  int tid = threadIdx.x;
  int w = tid >> 6, lane = tid & 63;
  int row0 = blockIdx.x * 16;         // 512 blocks
  int b = row0 >> 10;

  if (tid < 256) {
    int r = tid >> 4;                 // 0..15
    int cc = (tid & 15) * 8;          // k: 0,8,...,120
    int byte = r * 256 + ((cc * 2) ^ ((r & 7) << 4));
    *(bf16x8*)((char*)Ah + byte) = *(const bf16x8*)(packH + (size_t)(row0 + r) * 128 + cc);
    *(bf16x8*)((char*)Am + byte) = *(const bf16x8*)(packM + (size_t)(row0 + r) * 128 + cc);
    *(bf16x8*)((char*)Al + byte) = *(const bf16x8*)(packL + (size_t)(row0 + r) * 128 + cc);
  }
  __syncthreads();

  int lrow = lane & 15, kgrp = lane >> 4;
  const bf16* bH = packH + (size_t)b * 1024 * 128;
  const bf16* bM = packM + (size_t)b * 1024 * 128;
  const bf16* bL = packL + (size_t)b * 1024 * 128;
  int abase = lrow * 256;

  for (int half = 0; half < 2; ++half) {
    f32x4 acc[4];
    #pragma unroll
    for (int f = 0; f < 4; ++f) acc[f] = (f32x4){0.f, 0.f, 0.f, 0.f};

    for (int ks = 0; ks < nks; ++ks) {
      int kb = (ks * 32 + kgrp * 8) * 2;
      int aoff = abase + (kb ^ ((lrow & 7) << 4));
      bf16x8 a_h = *(const bf16x8*)((const char*)Ah + aoff);
      bf16x8 a_m = *(const bf16x8*)((const char*)Am + aoff);
      bf16x8 a_l = *(const bf16x8*)((const char*)Al + aoff);
      int kbase = ks * 32 + kgrp * 8;
      #pragma unroll
      for (int f = 0; f < 4; ++f) {
        int col = w * 128 + (half * 4 + f) * 16 + lrow;
        bf16x8 b_h = *(const bf16x8*)(bH + (size_t)col * 128 + kbase);
        bf16x8 b_m = *(const bf16x8*)(bM + (size_t)col * 128 + kbase);
        bf16x8 b_l = *(const bf16x8*)(bL + (size_t)col * 128 + kbase);
        acc[f] = __builtin_amdgcn_mfma_f32_16x16x32_bf16(a_h, b_h, acc[f], 0, 0, 0);
        acc[f] = __builtin_amdgcn_mfma_f32_16x16x32_bf16(a_h, b_m, acc[f], 0, 0, 0);
        acc[f] = __builtin_amdgcn_mfma_f32_16x16x32_bf16(a_m, b_h, acc[f], 0, 0, 0);
        acc[f] = __builtin_amdgcn_mfma_f32_16x16x32_bf16(a_m, b_m, acc[f], 0, 0, 0);
        acc[f] = __builtin_amdgcn_mfma_f32_16x16x32_bf16(a_h, b_l, acc[f], 0, 0, 0);
        acc[f] = __builtin_amdgcn_mfma_f32_16x16x32_bf16(a_l, b_h, acc[f], 0, 0, 0);
        acc[f] = __builtin_amdgcn_mfma_f32_16x16x32_bf16(a_m, b_l, acc[f], 0, 0, 0);
        acc[f] = __builtin_amdgcn_mfma_f32_16x16x32_bf16(a_l, b_m, acc[f], 0, 0, 0);
      }
    }
    // D epilogue (m89-verified layout: row=(lane>>4)*4+r, col=lane&15)
    #pragma unroll
    for (int f = 0; f < 4; ++f) {
      int col = w * 128 + (half * 4 + f) * 16 + lrow;
      #pragma unroll
      for (int r = 0; r < 4; ++r)
        Ds[(kgrp * 4 + r) * 1028 + col] = acc[f][r];
    }
  }
  __syncthreads();

  // selection: wave w handles rows 2w, 2w+1 (R11 passer, verbatim semantics)
  const float* x2b = x2 + b * N_PTS;
  for (int r2 = 0; r2 < 2; ++r2) {
    int rloc = w * 2 + r2;
    int row = row0 + rloc;
    float x2n = x2[row];
    float accv[16];
    #pragma unroll
    for (int j = 0; j < 16; ++j) {
      float d = Ds[rloc * 1028 + j * 64 + lane];
      accv[j] = (2.f * d - x2n) - x2b[j * 64 + lane];
    }

    for (int rr = 0; rr < KNN_K; ++rr) {
      float m01 = fmaxf(accv[0], accv[1]),   m23 = fmaxf(accv[2], accv[3]);
      float m45 = fmaxf(accv[4], accv[5]),   m67 = fmaxf(accv[6], accv[7]);
      float m89 = fmaxf(accv[8], accv[9]),   mab = fmaxf(accv[10], accv[11]);
      float mcd = fmaxf(accv[12], accv[13]), mef = fmaxf(accv[14], accv[15]);
      float mx = fmaxf(fmaxf(fmaxf(m01, m23), fmaxf(m45, m67)),
                       fmaxf(fmaxf(m89, mab), fmaxf(mcd, mef)));
      DPP_MAX_STAGE(0x111)
      DPP_MAX_STAGE(0x112)
      DPP_MAX_STAGE(0x114)
      DPP_MAX_STAGE(0x118)
      DPP_MAX_STAGE(0x142)
      DPP_MAX_STAGE(0x143)
      mx = __int_as_float(__builtin_amdgcn_readlane(__float_as_int(mx), 63));

      int jloc = 16;
      #pragma unroll
      for (int j = 15; j >= 0; --j)
        if (accv[j] == mx) jloc = j;
      int mc = (jloc < 16) ? ((jloc << 6) | lane) : 0x7fffffff;
      DPP_MIN_STAGE(0x111)
      DPP_MIN_STAGE(0x112)
      DPP_MIN_STAGE(0x114)
      DPP_MIN_STAGE(0x118)
      DPP_MIN_STAGE(0x142)
      DPP_MIN_STAGE(0x143)
      int si = __builtin_amdgcn_readlane(mc, 63);

      int jj = si >> 6, ln = si & 63;
      bool isln = (lane == ln);
      #pragma unroll
      for (int j = 0; j < 16; ++j)
        if (j == jj && isln) accv[j] = -3.4e38f;
      if (lane == 0) idxout[row * KNN_K + rr] = si;
    }
  }
}

// ---------------- build combined weight Wc (fp32): [w1-w2 | w2], K=C rows x 2O cols ----------------
__global__ __launch_bounds__(256) void build_wc(const float* __restrict__ w, int C, int O,
                                                float* __restrict__ wc) {
  int t = blockIdx.x * 256 + threadIdx.x;
  int twoO = 2 * O;
  if (t >= C * twoO) return;
  int c = t / twoO, j = t - c * twoO;
  float v;
  if (j < O) v = w[j * (2 * C) + c] - w[j * (2 * C) + C + c];
  else       v = w[(j - O) * (2 * C) + C + c];
  wc[t] = v;
}

// ---------------- fp32 GEMM (edge layers): C[M,N] = A[M,K](lda) * B[K,N] ----------------
__global__ __launch_bounds__(256) void gemm_kernel(const float* __restrict__ A, int lda,
                                                   const float* __restrict__ Bm,
                                                   float* __restrict__ Cm,
                                                   int M, int N, int K) {
  __shared__ float As[16][64];
  __shared__ float Bs[16][68];
  int tx = threadIdx.x & 15, ty = threadIdx.x >> 4;
  int bn0 = blockIdx.x * 64, bm0 = blockIdx.y * 64;
  float acc[4][4];
  #pragma unroll
  for (int i = 0; i < 4; ++i)
    #pragma unroll
    for (int j = 0; j < 4; ++j) acc[i][j] = 0.f;

  for (int k0 = 0; k0 < K; k0 += 16) {
    {
      int t = threadIdx.x;
      int m = t >> 2, kb = (t & 3) * 4;
      const float* ap = A + (size_t)(bm0 + m) * lda + k0 + kb;
      #pragma unroll
      for (int i = 0; i < 4; ++i) As[kb + i][m] = (k0 + kb + i < K) ? ap[i] : 0.f;
      int r = t >> 4, c4 = (t & 15) * 4;
      float4 bv = make_float4(0.f, 0.f, 0.f, 0.f);
      if (k0 + r < K) bv = *(const float4*)(Bm + (size_t)(k0 + r) * N + bn0 + c4);
      *(float4*)&Bs[r][c4] = bv;
    }
    __syncthreads();
    #pragma unroll
    for (int k = 0; k < 16; ++k) {
      float a0[4];
      #pragma unroll
      for (int i = 0; i < 4; ++i) a0[i] = As[k][ty * 4 + i];
      float4 bv = *(const float4*)&Bs[k][tx * 4];
      float b0[4] = {bv.x, bv.y, bv.z, bv.w};
      #pragma unroll
      for (int i = 0; i < 4; ++i)
        #pragma unroll
        for (int j = 0; j < 4; ++j) acc[i][j] = fmaf(a0[i], b0[j], acc[i][j]);
    }
    __syncthreads();
  }
  #pragma unroll
  for (int i = 0; i < 4; ++i) {
    float4 v = make_float4(acc[i][0], acc[i][1], acc[i][2], acc[i][3]);
    *(float4*)(Cm + (size_t)(bm0 + ty * 4 + i) * N + bn0 + tx * 4) = v;
  }
}

// ---------------- split fp32 -> bf16 hi/lo MFMA GEMM for layer 5, fused reduction ----------------
__device__ inline void split8(const float* __restrict__ p, bf16x8* hv, bf16x8* lv) {
  float4 a0 = *(const float4*)p, a1 = *(const float4*)(p + 4);
  float v[8] = {a0.x, a0.y, a0.z, a0.w, a1.x, a1.y, a1.z, a1.w};
  bf16x8 h, l;
  #pragma unroll
  for (int j = 0; j < 8; ++j) {
    bf16 hj = (bf16)v[j];
    h[j] = hj;
    l[j] = (bf16)(v[j] - (float)hj);
  }
  *hv = h; *lv = l;
}

__global__ __launch_bounds__(256) void gemm_split_red(const float* __restrict__ A, int lda,
                                                      const float* __restrict__ Bt, int ldb,
                                                      float* __restrict__ parts, int K) {
  __shared__ u16 Ah[128 * 64];
  __shared__ u16 Al[128 * 64];
  __shared__ u16 Bh[128 * 64];
  __shared__ u16 Bl[128 * 64];
  int tid = threadIdx.x;
  int wave = tid >> 6, lane = tid & 63;
  int wr = wave >> 1, wc = wave & 1;
  int bn0 = blockIdx.x * 128, bm0 = blockIdx.y * 128;
  int lrow = lane & 15;
  int kgrp = lane >> 4;

  f32x4 acc[4][4];
  #pragma unroll
  for (int i = 0; i < 4; ++i)
    #pragma unroll
    for (int j = 0; j < 4; ++j) acc[i][j] = (f32x4){0.f, 0.f, 0.f, 0.f};

  for (int k0 = 0; k0 < K; k0 += 64) {
    #pragma unroll
    for (int i = 0; i < 4; ++i) {
      int chunk = tid + i * 256;
      int row = chunk >> 3;
      int cc = (chunk & 7) * 8;
      int byte = row * 128 + ((cc * 2) ^ ((row & 7) << 4));
      bf16x8 h, l;
      split8(A + (size_t)(bm0 + row) * lda + k0 + cc, &h, &l);
      *(bf16x8*)((char*)Ah + byte) = h;
      *(bf16x8*)((char*)Al + byte) = l;
      split8(Bt + (size_t)(bn0 + row) * ldb + k0 + cc, &h, &l);
      *(bf16x8*)((char*)Bh + byte) = h;
      *(bf16x8*)((char*)Bl + byte) = l;
    }
    __syncthreads();
    #pragma unroll
    for (int kk = 0; kk < 64; kk += 32) {
      int kb = (kk + kgrp * 8) * 2;
      bf16x8 afh[4], afl[4], bfh[4], bfl[4];
      #pragma unroll
      for (int f = 0; f < 4; ++f) {
        int arow = wr * 64 + f * 16 + lrow;
        int abyte = arow * 128 + (kb ^ ((arow & 7) << 4));
        afh[f] = *(const bf16x8*)((const char*)Ah + abyte);
        afl[f] = *(const bf16x8*)((const char*)Al + abyte);
        int brow = wc * 64 + f * 16 + lrow;
        int bbyte = brow * 128 + (kb ^ ((brow & 7) << 4));
        bfh[f] = *(const bf16x8*)((const char*)Bh + bbyte);
        bfl[f] = *(const bf16x8*)((const char*)Bl + bbyte);
      }
      #pragma unroll
      for (int fm = 0; fm < 4; ++fm)
        #pragma unroll
        for (int fn = 0; fn < 4; ++fn) {
          acc[fm][fn] = __builtin_amdgcn_mfma_f32_16x16x32_bf16(afh[fm], bfh[fn], acc[fm][fn], 0, 0, 0);
          acc[fm][fn] = __builtin_amdgcn_mfma_f32_16x16x32_bf16(afl[fm], bfh[fn], acc[fm][fn], 0, 0, 0);
          acc[fm][fn] = __builtin_amdgcn_mfma_f32_16x16x32_bf16(afh[fm], bfl[fn], acc[fm][fn], 0, 0, 0);
        }
    }
    __syncthreads();
  }

  float* scratch = (float*)Ah;
  int contrib = wr * 4 + kgrp;
  #pragma unroll
  for (int fn = 0; fn < 4; ++fn) {
    float mx = -3.4e38f, mn = 3.4e38f, s1 = 0.f, s2 = 0.f;
    #pragma unroll
    for (int fm = 0; fm < 4; ++fm)
      #pragma unroll
      for (int r = 0; r < 4; ++r) {
        float v = acc[fm][fn][r];
        mx = fmaxf(mx, v); mn = fminf(mn, v);
        s1 += v; s2 = fmaf(v, v, s2);
      }
    int col = wc * 64 + fn * 16 + lrow;
    float* sp = scratch + (contrib * 128 + col) * 4;
    sp[0] = mx; sp[1] = mn; sp[2] = s1; sp[3] = s2;
  }
  __syncthreads();
  if (tid < 128) {
    float mx = -3.4e38f, mn = 3.4e38f, s1 = 0.f, s2 = 0.f;
    #pragma unroll
    for (int c2 = 0; c2 < 8; ++c2) {
      const float* sp = scratch + (c2 * 128 + tid) * 4;
      mx = fmaxf(mx, sp[0]); mn = fminf(mn, sp[1]);
      s1 += sp[2]; s2 += sp[3];
    }
    size_t o = (size_t)blockIdx.y * 1024 + bn0 + tid;
    parts[o] = mx;
    parts[65536 + o] = mn;
    parts[131072 + o] = s1;
    parts[196608 + o] = s2;
  }
}

// ---------------- edge aggregation: h = a + y[idx]; max/min over k + channel sums ----------------
__global__ __launch_bounds__(256) void aggregate_kernel(const float* __restrict__ ay,
                                                        const int* __restrict__ idxb, int O,
                                                        float* __restrict__ mx,
                                                        float* __restrict__ mn,
                                                        float* __restrict__ sumsbin) {
  __shared__ float ls[2][256];
  for (int i = threadIdx.x; i < 512; i += 256) ((float*)ls)[i] = 0.f;
  __syncthreads();

  int warp = threadIdx.x >> 6, lane = threadIdx.x & 63;
  int pt = blockIdx.x * 4 + warp;
  int b = pt >> 10;
  int twoO = 2 * O;
  int U = O >> 6;
  const float* ayrow = ay + (size_t)pt * twoO;

  float av[4], s1[4], s2[4], vmx[4], vmn[4];
  for (int u = 0; u < U; ++u) {
    av[u] = ayrow[u * 64 + lane];
    s1[u] = 0.f; s2[u] = 0.f; vmx[u] = -3.4e38f; vmn[u] = 3.4e38f;
  }
  const int* ip = idxb + pt * KNN_K;
  for (int k = 0; k < KNN_K; ++k) {
    int j = ip[k];
    const float* yrow = ay + (size_t)(b * N_PTS + j) * twoO + O;
    for (int u = 0; u < U; ++u) {
      float v = av[u] + yrow[u * 64 + lane];
      s1[u] += v; s2[u] = fmaf(v, v, s2[u]);
      vmx[u] = fmaxf(vmx[u], v); vmn[u] = fminf(vmn[u], v);
    }
  }
  for (int u = 0; u < U; ++u) {
    int o = u * 64 + lane;
    mx[(size_t)pt * O + o] = vmx[u];
    mn[(size_t)pt * O + o] = vmn[u];
    atomicAdd(&ls[0][o], s1[u]);
    atomicAdd(&ls[1][o], s2[u]);
  }
  __syncthreads();
  int bin = blockIdx.x & 63;
  float* gb = sumsbin + (size_t)bin * 512;
  for (int o = threadIdx.x; o < O; o += 256) {
    atomicAdd(&gb[o], ls[0][o]);
    atomicAdd(&gb[256 + o], ls[1][o]);
  }
}

__global__ __launch_bounds__(256) void reduce_bins(const float* __restrict__ sumsbin,
                                                   float* __restrict__ sums, int O) {
  int o = threadIdx.x;
  if (o >= O) return;
  float a = 0.f, c = 0.f;
  for (int bin = 0; bin < 64; ++bin) {
    a += sumsbin[bin * 512 + o];
    c += sumsbin[bin * 512 + 256 + o];
  }
  sums[o] = a;
  sums[256 + o] = c;
}

// ---------------- finalize edge layer: BN + relu on (max or min depending on sign) ----------------
__global__ __launch_bounds__(256) void finalize_edge(const float* __restrict__ mx,
                                                     const float* __restrict__ mn,
                                                     const float* __restrict__ sums,
                                                     const float* __restrict__ g,
                                                     const float* __restrict__ beta,
                                                     int oshift,
                                                     float* __restrict__ outseg,
                                                     float cnt_inv) {
  int tid = blockIdx.x * 256 + threadIdx.x;
  int pt = tid >> oshift;
  int o = tid & ((1 << oshift) - 1);
  float s1 = sums[o], s2 = sums[256 + o];
  float mean = s1 * cnt_inv;
  float var = s2 * cnt_inv - mean * mean;
  float rstd = rsqrtf(var + BN_EPS);
  float sc = g[o] * rstd;
  float sel = (sc >= 0.f) ? mx[tid] : mn[tid];
  float v = (sel - mean) * sc + beta[o];
  outseg[(size_t)pt * CAT_C + o] = fmaxf(v, 0.f);
}

// ---------------- layer 5 finalize from tile partials ----------------
__global__ __launch_bounds__(256) void finalize5_fused(const float* __restrict__ parts,
                                                       const float* __restrict__ g,
                                                       const float* __restrict__ beta,
                                                       float* __restrict__ out) {
  int tid = blockIdx.x * 256 + threadIdx.x;
  int b = tid >> 10, o = tid & 1023;
  const float* pmx = parts;
  const float* pmn = parts + 65536;
  const float* ps1 = parts + 131072;
  const float* ps2 = parts + 196608;
  float s1 = 0.f, s2 = 0.f;
  for (int t = 0; t < 64; ++t) { s1 += ps1[t * 1024 + o]; s2 += ps2[t * 1024 + o]; }
  float mx = -3.4e38f, mn = 3.4e38f;
  #pragma unroll
  for (int t = 0; t < 8; ++t) {
    mx = fmaxf(mx, pmx[(b * 8 + t) * 1024 + o]);
    mn = fminf(mn, pmn[(b * 8 + t) * 1024 + o]);
  }
  float mean = s1 * (1.0f / 8192.0f);
  float var = s2 * (1.0f / 8192.0f) - mean * mean;
  float rstd = rsqrtf(var + BN_EPS);
  float sc = g[o] * rstd;
  float sel = (sc >= 0.f) ? mx : mn;
  float v = (sel - mean) * sc + beta[o];
  out[tid] = fmaxf(v, 0.f);
}

extern "C" void kernel_launch(void* const* d_in, const int* in_sizes, int n_in,
                              void* d_out, int out_size, void* d_ws, size_t ws_size,
                              hipStream_t stream) {
  const float* x = (const float*)d_in[0];
  const float* w[5]  = {(const float*)d_in[1], (const float*)d_in[4], (const float*)d_in[7],
                        (const float*)d_in[10], (const float*)d_in[13]};
  const float* gg[5] = {(const float*)d_in[2], (const float*)d_in[5], (const float*)d_in[8],
                        (const float*)d_in[11], (const float*)d_in[14]};
  const float* bb[5] = {(const float*)d_in[3], (const float*)d_in[6], (const float*)d_in[9],
                        (const float*)d_in[12], (const float*)d_in[15]};
  float* out = (float*)d_out;

  float* W = (float*)d_ws;
  size_t off = 0;
  float* feat0   = W + off; off += (size_t)B_SZ * N_PTS * 4;   // stride-4 padded
  float* catbuf  = W + off; off += (size_t)8192 * CAT_C;
  int*   idxbuf  = (int*)(W + off); off += (size_t)8192 * KNN_K;
  float* aybuf   = W + off; off += (size_t)8192 * 1024;
  float* mxbuf   = W + off; off += (size_t)8192 * 256;
  float* mnbuf   = W + off; off += (size_t)8192 * 256;
  float* wcbuf   = W + off; off += (size_t)512 * 1024;
  float* sumsbin = W + off; off += (size_t)64 * 512;
  float* sums    = W + off; off += 512;
  float* parts   = W + off; off += (size_t)4 * 64 * 1024;
  float* x2buf   = W + off; off += 8192;
  bf16*  packH   = (bf16*)(W + off); off += (size_t)8192 * 128 / 2;   // 2MB
  bf16*  packM   = (bf16*)(W + off); off += (size_t)8192 * 128 / 2;   // 2MB
  bf16*  packL   = (bf16*)(W + off); off += (size_t)8192 * 128 / 2;   // 2MB

  hipMemsetAsync(feat0, 0, (size_t)B_SZ * N_PTS * 4 * sizeof(float), stream);
  transpose_x<<<(B_SZ * 3 * N_PTS + 255) / 256, 256, 0, stream>>>(x, feat0);

  const int Cs[4] = {4, 64, 64, 128};   // layer-0 padded to 4 (pad=0, values unchanged)
  const int Ks[4] = {3, 64, 64, 128};   // true K for the edge GEMM
  const int Os[4] = {64, 64, 128, 256};
  const int osh[4] = {6, 6, 7, 8};
  const int segin[4] = {0, 0, 64, 128};
  const int segout[4] = {0, 64, 128, 256};

  for (int l = 0; l < 4; ++l) {
    int C = Cs[l], O = Os[l], twoO = 2 * O;
    const float* featin = (l == 0) ? feat0 : (catbuf + segin[l]);
    int lda = (l == 0) ? 4 : CAT_C;
    int nks = (C + 31) / 32;            // 1,2,2,4

    xnorm_kernel<<<32, 256, 0, stream>>>(featin, lda, C, x2buf);
    split_pack<<<512, 256, 0, stream>>>(featin, lda, C, packH, packM, packL);
    knn_mfma<<<512, 512, 0, stream>>>(packH, packM, packL, x2buf, nks, idxbuf);

    build_wc<<<(Ks[l] * twoO + 255) / 256, 256, 0, stream>>>(w[l], Ks[l], O, wcbuf);
    gemm_kernel<<<dim3(twoO / 64, 8192 / 64), 256, 0, stream>>>(featin, lda, wcbuf, aybuf,
                                                                8192, twoO, Ks[l]);
    hipMemsetAsync(sumsbin, 0, (size_t)64 * 512 * sizeof(float), stream);
    aggregate_kernel<<<2048, 256, 0, stream>>>(aybuf, idxbuf, O, mxbuf, mnbuf, sumsbin);
    reduce_bins<<<1, 256, 0, stream>>>(sumsbin, sums, O);
    finalize_edge<<<(8192 * O) / 256, 256, 0, stream>>>(mxbuf, mnbuf, sums, gg[l], bb[l],
                                                        osh[l], catbuf + segout[l],
                                                        1.0f / (8192.0f * KNN_K));
  }

  // layer 5: h5 = cat * w5^T via split-bf16 MFMA with fused per-tile reduction
  gemm_split_red<<<dim3(1024 / 128, 8192 / 128), 256, 0, stream>>>(catbuf, CAT_C, w[4], 512,
                                                                   parts, 512);
  finalize5_fused<<<8192 / 256, 256, 0, stream>>>(parts, gg[4], bb[4], out);
}